// Round 9
// baseline (746.199 us; speedup 1.0000x reference)
//
#include <hip/hip_runtime.h>

#define HEADS 16
#define SEQ   2048
#define HID   1024
#define CACHE 2048
#define KVLEN 4096
#define MROWS 4096      // B*S
#define KD    2048      // GEMM inner dim (2*HID: real||imag)

typedef float  f32x4  __attribute__((ext_vector_type(4)));
typedef __bf16 bf16x4 __attribute__((ext_vector_type(4)));
typedef __bf16 bf16x8 __attribute__((ext_vector_type(8)));

__device__ __forceinline__ void gload_lds16(const void* g, void* l) {
  __builtin_amdgcn_global_load_lds((const __attribute__((address_space(1))) void*)g,
                                   (__attribute__((address_space(3))) void*)l, 16, 0, 0);
}

// ---------------- complex layernorm -> bf16 [4096][2048] (real||imag) ----------------
__global__ __launch_bounds__(256) void k_layernorm(const float* __restrict__ hid,
                                                   const float* __restrict__ gamma,
                                                   const float* __restrict__ beta,
                                                   __bf16* __restrict__ normed) {
  int row = blockIdx.x;                    // b*2048 + s
  int t = threadIdx.x;
  const float* xr = hid + (size_t)row * HID;
  const float* xi = hid + (size_t)MROWS * HID + (size_t)row * HID;
  float vr[4], vi[4];
  float sr = 0.f, si = 0.f;
#pragma unroll
  for (int i = 0; i < 4; i++) { int h = t + i * 256; vr[i] = xr[h]; vi[i] = xi[h]; sr += vr[i]; si += vi[i]; }
  __shared__ float red[2][4];
  for (int m = 1; m < 64; m <<= 1) { sr += __shfl_xor(sr, m); si += __shfl_xor(si, m); }
  int wid = t >> 6, l = t & 63;
  if (l == 0) { red[0][wid] = sr; red[1][wid] = si; }
  __syncthreads();
  float mr = (red[0][0] + red[0][1] + red[0][2] + red[0][3]) * (1.0f / HID);
  float mi = (red[1][0] + red[1][1] + red[1][2] + red[1][3]) * (1.0f / HID);
  float sv = 0.f;
#pragma unroll
  for (int i = 0; i < 4; i++) { float a = vr[i] - mr, b = vi[i] - mi; sv += a * a + b * b; }
  for (int m = 1; m < 64; m <<= 1) sv += __shfl_xor(sv, m);
  __syncthreads();
  if (l == 0) red[0][wid] = sv;
  __syncthreads();
  float var = (red[0][0] + red[0][1] + red[0][2] + red[0][3]) * (1.0f / HID);
  float inv = rsqrtf(var + 1e-5f);
  __bf16* outr = normed + (size_t)row * KD;
#pragma unroll
  for (int i = 0; i < 4; i++) {
    int h = t + i * 256;
    float a = (vr[i] - mr) * inv, b = (vi[i] - mi) * inv;
    float gr = gamma[h], gi = gamma[HID + h], br = beta[h], bi = beta[HID + h];
    outr[h]       = (__bf16)(a * gr - b * gi + br);
    outr[HID + h] = (__bf16)(a * gi + b * gr + bi);
  }
}

// ---------------- pack 4 complex weights [2,1024,1024] -> real B^T [4][2048][2048] bf16 ----------------
__global__ __launch_bounds__(256) void k_packw(const float* __restrict__ qw, const float* __restrict__ kw,
                                               const float* __restrict__ vw, const float* __restrict__ ow,
                                               __bf16* __restrict__ dst) {
  int idx = blockIdx.x * 256 + threadIdx.x;   // 2,097,152 threads, 8 elems each
  int sel = idx >> 19;                        // 0..3: q,k,v,o
  int li  = idx & 524287;
  const float* w = sel == 0 ? qw : (sel == 1 ? kw : (sel == 2 ? vw : ow));
  int o  = li >> 8;
  int k0 = (li & 255) * 8;
  const float* wr = w;
  const float* wi = w + HID * HID;
  int oimag = (o >= HID);
  int oo = o & (HID - 1);
  bf16x8 v;
#pragma unroll
  for (int j = 0; j < 8; j++) {
    int k = k0 + j;
    int kim = (k >= HID);
    int kk = k & (HID - 1);
    float x;
    if (!oimag) x = kim ? -wi[oo * HID + kk] : wr[oo * HID + kk];
    else        x = kim ?  wr[oo * HID + kk] : wi[oo * HID + kk];
    v[j] = (__bf16)x;
  }
  *(bf16x8*)(dst + ((size_t)sel << 22) + (size_t)o * KD + k0) = v;
}

// ---------------- K cache: fp32 copy into nk AND bf16 attn layout Ka ----------------
__global__ __launch_bounds__(256) void k_copyk(const float* __restrict__ kc,
                                               float* __restrict__ nk,
                                               __bf16* __restrict__ Ka) {
  int li = blockIdx.x * 256 + threadIdx.x;   // 2^21 float4 groups
  int c4 = li & 255;
  int kv = (li >> 8) & 2047;
  int b  = (li >> 19) & 1;
  int p  = (li >> 20) & 1;
  f32x4 v = *(const f32x4*)(kc + (((size_t)((p * 2 + b) * 2048 + kv)) << 10) + c4 * 4);
  *(f32x4*)(nk + ((((size_t)(p * 2 + b)) * KVLEN + kv) << 10) + c4 * 4) = v;
  int h = c4 >> 4, d = (c4 & 15) * 4;
  bf16x4 w;
#pragma unroll
  for (int j = 0; j < 4; j++) w[j] = (__bf16)v[j];
  *(bf16x4*)(Ka + (((size_t)(b * 16 + h)) * KVLEN + kv) * 128 + p * 64 + d) = w;
}

// ---------------- v_cache fp32 -> nv fp32 copy + Vattn bf16 transposed (cache half) --------
__global__ __launch_bounds__(256) void k_buildv(const float* __restrict__ vc,
                                                float* __restrict__ nv,
                                                __bf16* __restrict__ dst) {
  __shared__ float tile[32][129];
  int kt = blockIdx.x;            // kv tile (32 rows), 64 tiles = cache half
  int bh = blockIdx.y;
  int b = bh >> 4, h = bh & 15;
  int t = threadIdx.x;
  int kv0 = kt * 32;
#pragma unroll
  for (int i = 0; i < 16; i++) {
    int idx = i * 256 + t;
    int kvl = idx >> 7, dsl = idx & 127;
    int p = dsl >> 6, d = dsl & 63;
    float v = vc[(((size_t)(p * 2 + b)) * CACHE + kv0 + kvl) * HID + h * 64 + d];
    tile[kvl][dsl] = v;
    nv[(((size_t)(p * 2 + b)) * KVLEN + kv0 + kvl) * HID + h * 64 + d] = v;
  }
  __syncthreads();
#pragma unroll
  for (int i = 0; i < 16; i++) {
    int idx = i * 256 + t;
    int dsl = idx >> 5, kvl = idx & 31;
    dst[(((size_t)bh) * 128 + dsl) * KVLEN + kv0 + kvl] = (__bf16)tile[kvl][dsl];
  }
}

// ---------------- bf16 GEMM 128x128 tile, BK=64, 4 waves, T2 XOR-swizzled LDS ----------------
// QKV=1: A=normed, B=[wq;wk;wv] (N=6144), n>>11 selects {Qa | nk+Ka | nv+Va} epilogue
// QKV=0: A=attn_out, B=wo, y = x + delta
#define BM 128
#define BN 128
#define BK 64
template <int QKV>
__global__ __launch_bounds__(256, 3) void k_gemm(const __bf16* __restrict__ A,
                                                 const __bf16* __restrict__ Bp,
                                                 const float* __restrict__ bias0,
                                                 const float* __restrict__ bias1,
                                                 const float* __restrict__ bias2,
                                                 const float* __restrict__ hid,
                                                 float* __restrict__ outF0,
                                                 float* __restrict__ outF1,
                                                 __bf16* __restrict__ outB0,
                                                 __bf16* __restrict__ outB1,
                                                 __bf16* __restrict__ outB2) {
  __shared__ __align__(16) __bf16 As[BM * BK];
  __shared__ __align__(16) __bf16 Bs[BN * BK];
  int bm0 = blockIdx.x * BM, bn0 = blockIdx.y * BN;
  int t = threadIdx.x, l = t & 63, wid = t >> 6;
  int wr = wid >> 1, wc = wid & 1;
  int l15 = l & 15, lg = l >> 4;
  f32x4 acc[4][4];
  f32x4 zero = {0.f, 0.f, 0.f, 0.f};
#pragma unroll
  for (int i = 0; i < 4; i++)
#pragma unroll
    for (int j = 0; j < 4; j++) acc[i][j] = zero;
  const __bf16* Ab = A + (size_t)bm0 * KD;
  const __bf16* Bb = Bp + (size_t)bn0 * KD;
  for (int k0 = 0; k0 < KD; k0 += BK) {
    // stage: LDS dest linear (global_load_lds), global source column pre-swizzled:
    // LDS[row][slot s] = global[row][s ^ (row&7)]  (16B slots)
#pragma unroll
    for (int c = 0; c < 4; c++) {
      int idx = c * 256 + t;
      int row = idx >> 3, ch = idx & 7;
      int chs = ch ^ (row & 7);
      gload_lds16(Ab + (size_t)row * KD + k0 + chs * 8, As + idx * 8);
      gload_lds16(Bb + (size_t)row * KD + k0 + chs * 8, Bs + idx * 8);
    }
    __syncthreads();
#pragma unroll
    for (int ks = 0; ks < 2; ks++) {
      bf16x8 af[4], bfv[4];
#pragma unroll
      for (int i = 0; i < 4; i++) {
        int ra = wr * 64 + i * 16 + l15;
        int rb = wc * 64 + i * 16 + l15;
        af[i]  = *(const bf16x8*)((const char*)As + ra * 128 + ((ks * 64 + lg * 16) ^ ((ra & 7) << 4)));
        bfv[i] = *(const bf16x8*)((const char*)Bs + rb * 128 + ((ks * 64 + lg * 16) ^ ((rb & 7) << 4)));
      }
#pragma unroll
      for (int mi = 0; mi < 4; mi++)
#pragma unroll
        for (int ni = 0; ni < 4; ni++)
          acc[mi][ni] = __builtin_amdgcn_mfma_f32_16x16x32_bf16(af[mi], bfv[ni], acc[mi][ni], 0, 0, 0);
    }
    __syncthreads();
  }
  // epilogue: C[m][n]: m row = (lg*4+j), col = l15 within each 16x16 frag
#pragma unroll
  for (int mi = 0; mi < 4; mi++) {
#pragma unroll
    for (int ni = 0; ni < 4; ni++) {
      int mbase = bm0 + wr * 64 + mi * 16 + lg * 4;     // 4 consecutive m over j
      int n = bn0 + wc * 64 + ni * 16 + l15;
      int b = mbase >> 11, sbase = mbase & 2047;
      if (QKV) {
        int mode = n >> 11, nl = n & 2047;
        const float* bias = mode == 0 ? bias0 : (mode == 1 ? bias1 : bias2);
        float bv = bias[nl];
        int p = nl >> 10, hd = nl & 1023;
        if (mode == 2) {
          bf16x4 w;
#pragma unroll
          for (int j = 0; j < 4; j++) {
            float v = acc[mi][ni][j] + bv;
            outF1[(((size_t)(p * 2 + b)) * KVLEN + (CACHE + sbase + j)) * HID + hd] = v;
            w[j] = (__bf16)v;
          }
          *(bf16x4*)(outB2 + (((size_t)(b * 16 + (hd >> 6))) * 128 + p * 64 + (hd & 63)) * KVLEN + CACHE + sbase) = w;
        } else {
#pragma unroll
          for (int j = 0; j < 4; j++) {
            float v = acc[mi][ni][j] + bv;
            int s = sbase + j;
            if (mode == 0) {
              outB0[(((size_t)(b * 16 + (hd >> 6))) * SEQ + s) * 128 + p * 64 + (hd & 63)] = (__bf16)v;
            } else {
              outF0[(((size_t)(p * 2 + b)) * KVLEN + (CACHE + s)) * HID + hd] = v;
              outB1[(((size_t)(b * 16 + (hd >> 6))) * KVLEN + (CACHE + s)) * 128 + p * 64 + (hd & 63)] = (__bf16)v;
            }
          }
        }
      } else {
        float bv = bias0[n];
        int p = n >> 10;
#pragma unroll
        for (int j = 0; j < 4; j++) {
          float v = acc[mi][ni][j] + bv;
          size_t off = (((size_t)(p * 2 + b)) * SEQ + (sbase + j)) * HID + (n & 1023);
          outF0[off] = v + hid[off];
        }
      }
    }
  }
}

// ---------------- flash attention: 4 waves x 16 q-rows, 64-kv tiles, d=128 ----------------
// Single-buffered K/V (40 KB LDS -> 4 blocks/CU, cross-block TLP hides staging latency).
// Swapped QK^T, packed bf16x4 P writes, no online max (bounded logits), ones-MFMA row-sum.
__global__ __launch_bounds__(256, 4) void k_attn(const __bf16* __restrict__ Q,
                                                 const __bf16* __restrict__ Kt,
                                                 const __bf16* __restrict__ Vt,
                                                 __bf16* __restrict__ outp) {
  __shared__ __align__(16) __bf16 Ks[64 * 128];
  __shared__ __align__(16) __bf16 Vs[128 * 64];
  __shared__ __align__(16) __bf16 Ps[4][16 * 64];
  // 1024 blocks: XCD-chunked (4 heads/XCD) + qt pairing (qt, 31-qt) for balance
  int id = blockIdx.y * gridDim.x + blockIdx.x;
  int xcd = id & 7, li = id >> 3;
  int bh = (xcd << 2) | (li >> 5);
  int ql = li & 31;
  int qt = (ql & 1) ? (31 - (ql >> 1)) : (ql >> 1);
  int b = bh >> 4, h = bh & 15;
  int t = threadIdx.x, l = t & 63, wid = t >> 6;
  int l15 = l & 15, lg = l >> 4;
  const __bf16* Qb = Q + ((size_t)bh * SEQ) * 128;
  const __bf16* Kb = Kt + ((size_t)bh * KVLEN) * 128;
  const __bf16* Vb = Vt + ((size_t)bh * 128) * KVLEN;
  __bf16* Pw = &Ps[wid][0];
  int q0 = qt * 64 + wid * 16;
  bf16x8 aQ[4];
#pragma unroll
  for (int dk = 0; dk < 4; dk++)
    aQ[dk] = *(const bf16x8*)(Qb + (size_t)(q0 + l15) * 128 + dk * 32 + lg * 8);
  f32x4 zero = {0.f, 0.f, 0.f, 0.f};
  f32x4 o[8];
  f32x4 sums = zero;
#pragma unroll
  for (int df = 0; df < 8; df++) o[df] = zero;
  bf16x8 ones;
#pragma unroll
  for (int i = 0; i < 8; i++) ones[i] = (__bf16)1.0f;
  const int nfull = 32 + qt;     // unmasked 64-kv tiles
  const int nt = nfull + 1;      // + diagonal tile
  int sw = (l15 & 7) << 4;
  int row = l15;                 // P row (q within wave's 16)
  int rx = (row & 7) << 3;

  for (int ti = 0; ti < nt; ti++) {
    int kv0 = ti * 64;
    // ---- stage K [64][128], V [128][64] (swizzled via pre-swizzled global source) ----
#pragma unroll
    for (int c = 0; c < 4; c++) {
      int idx = c * 256 + t;
      int kr = idx >> 4;
      gload_lds16(Kb + (size_t)(kv0 + kr) * 128 + (((idx & 15) ^ (kr & 7)) << 3), Ks + idx * 8);
      int vr = idx >> 3;
      gload_lds16(Vb + (size_t)vr * KVLEN + kv0 + (((idx & 7) ^ (vr & 7)) << 3), Vs + idx * 8);
    }
    asm volatile("s_waitcnt vmcnt(0)" ::: "memory");
    __builtin_amdgcn_s_barrier();
    // ---- QK^T (swapped: A=K, B=Q -> C row=kv-local, col=q-local) ----
    f32x4 sacc[4];
    __builtin_amdgcn_s_setprio(1);
#pragma unroll
    for (int kvf = 0; kvf < 4; kvf++) {
      sacc[kvf] = zero;
      const char* kbase = (const char*)Ks + (kvf * 16 + l15) * 256;
#pragma unroll
      for (int dk = 0; dk < 4; dk++) {
        bf16x8 bK = *(const bf16x8*)(kbase + ((dk * 64 + lg * 16) ^ sw));
        sacc[kvf] = __builtin_amdgcn_mfma_f32_16x16x32_bf16(bK, aQ[dk], sacc[kvf], 0, 0, 0);
      }
    }
    __builtin_amdgcn_s_setprio(0);
    // ---- softmax: lane owns q=l15, kv=kvf*16+lg*4+j -> packed bf16x4 P writes ----
    bool masked = (ti >= nfull);
#pragma unroll
    for (int kvf = 0; kvf < 4; kvf++) {
      bf16x4 w;
#pragma unroll
      for (int j = 0; j < 4; j++) {
        float p = exp2f(sacc[kvf][j] * 0.18033688011112042f);  // 1/sqrt(64)*log2(e)
        if (masked) {
          if (kvf * 16 + lg * 4 + j > wid * 16 + row) p = 0.f;
        }
        w[j] = (__bf16)p;
      }
      *(bf16x4*)(Pw + row * 64 + ((kvf * 16 + lg * 4) ^ rx)) = w;
    }
    // ---- hoist V and P fragments, then pure MFMA cluster ----
    bf16x8 bV[2][8], aP[2];
#pragma unroll
    for (int ks = 0; ks < 2; ks++) {
      int off = (ks * 64 + lg * 16) ^ sw;
#pragma unroll
      for (int df = 0; df < 8; df++)
        bV[ks][df] = *(const bf16x8*)((const char*)Vs + (df * 16 + l15) * 128 + off);
    }
    const __bf16* pb = Pw + row * 64;
#pragma unroll
    for (int ks = 0; ks < 2; ks++)
      aP[ks] = *(const bf16x8*)(pb + ((ks * 32 + lg * 8) ^ rx));
    __builtin_amdgcn_s_setprio(1);
#pragma unroll
    for (int ks = 0; ks < 2; ks++) {
      sums = __builtin_amdgcn_mfma_f32_16x16x32_bf16(aP[ks], ones, sums, 0, 0, 0);
#pragma unroll
      for (int df = 0; df < 8; df++)
        o[df] = __builtin_amdgcn_mfma_f32_16x16x32_bf16(aP[ks], bV[ks][df], o[df], 0, 0, 0);
    }
    __builtin_amdgcn_s_setprio(0);
    __builtin_amdgcn_s_barrier();   // all waves done with Ks/Vs before next stage overwrites
  }
  // ---- write attn_out [4096][2048] bf16 (real cols 0..1023, imag 1024..2047) ----
  float inv[4];
#pragma unroll
  for (int j = 0; j < 4; j++) inv[j] = 1.0f / sums[j];
#pragma unroll
  for (int df = 0; df < 8; df++) {
    int dslot = df * 16 + l15;
    int col = (dslot < 64) ? (h * 64 + dslot) : (1024 + h * 64 + (dslot - 64));
#pragma unroll
    for (int j = 0; j < 4; j++) {
      int qg2 = q0 + lg * 4 + j;
      float v = o[df][j] * inv[j];
      outp[((size_t)(b * SEQ + qg2)) * KD + col] = (__bf16)v;
    }
  }
}

extern "C" void kernel_launch(void* const* d_in, const int* in_sizes, int n_in,
                              void* d_out, int out_size, void* d_ws, size_t ws_size,
                              hipStream_t stream) {
  const float* hid = (const float*)d_in[0];
  const float* kc  = (const float*)d_in[1];
  const float* vc  = (const float*)d_in[2];
  const float* qw  = (const float*)d_in[3];
  const float* qb  = (const float*)d_in[4];
  const float* kw  = (const float*)d_in[5];
  const float* kb  = (const float*)d_in[6];
  const float* vw  = (const float*)d_in[7];
  const float* vb  = (const float*)d_in[8];
  const float* ow  = (const float*)d_in[9];
  const float* ob  = (const float*)d_in[10];
  const float* lg  = (const float*)d_in[11];
  const float* lb  = (const float*)d_in[12];

  float* y  = (float*)d_out;                 // [2,B,S,H]       8,388,608 f32
  float* nk = y + 8388608;                   // [2,B,4096,16,64] 16,777,216 f32
  float* nv = nk + 16777216;

  char* ws = (char*)d_ws;
  __bf16* normed = (__bf16*)(ws);                  // 16 MB [4096][2048]
  __bf16* wall   = (__bf16*)(ws + 16777216);       // 32 MB [4][2048][2048] q,k,v,o
  __bf16* Qa     = (__bf16*)(ws + 50331648);       // 16 MB [32][2048][128]
  __bf16* Ka     = (__bf16*)(ws + 67108864);       // 32 MB [32][4096][128]
  __bf16* Va     = (__bf16*)(ws + 100663296);      // 32 MB [32][128][4096]
  __bf16* ao     = (__bf16*)(ws + 134217728);      // 16 MB [4096][2048]

  k_layernorm<<<4096, 256, 0, stream>>>(hid, lg, lb, normed);
  k_packw<<<8192, 256, 0, stream>>>(qw, kw, vw, ow, wall);
  k_copyk<<<8192, 256, 0, stream>>>(kc, nk, Ka);
  dim3 gv(64, 32);
  k_buildv<<<gv, 256, 0, stream>>>(vc, nv, Va);
  dim3 gq(32, 48);
  k_gemm<1><<<gq, 256, 0, stream>>>(normed, wall, qb, kb, vb, nullptr, nk, nv, Qa, Ka, Va);
  dim3 ga(32, 32);
  k_attn<<<ga, 256, 0, stream>>>(Qa, Ka, Va, ao);
  dim3 go(32, 16);
  k_gemm<0><<<go, 256, 0, stream>>>(ao, wall + ((size_t)3 << 22), ob, nullptr, nullptr, hid, y, nullptr, nullptr, nullptr, nullptr);
}

// Round 10
// 432.562 us; speedup vs baseline: 1.7251x; 1.7251x over previous
//
#include <hip/hip_runtime.h>

#define HEADS 16
#define SEQ   2048
#define HID   1024
#define CACHE 2048
#define KVLEN 4096
#define MROWS 4096      // B*S
#define KD    2048      // GEMM inner dim (2*HID: real||imag)

typedef float  f32x4  __attribute__((ext_vector_type(4)));
typedef __bf16 bf16x4 __attribute__((ext_vector_type(4)));
typedef __bf16 bf16x8 __attribute__((ext_vector_type(8)));

__device__ __forceinline__ void gload_lds16(const void* g, void* l) {
  __builtin_amdgcn_global_load_lds((const __attribute__((address_space(1))) void*)g,
                                   (__attribute__((address_space(3))) void*)l, 16, 0, 0);
}

// ---------------- complex layernorm -> bf16 [4096][2048] (real||imag) ----------------
__global__ __launch_bounds__(256) void k_layernorm(const float* __restrict__ hid,
                                                   const float* __restrict__ gamma,
                                                   const float* __restrict__ beta,
                                                   __bf16* __restrict__ normed) {
  int row = blockIdx.x;                    // b*2048 + s
  int t = threadIdx.x;
  const float* xr = hid + (size_t)row * HID;
  const float* xi = hid + (size_t)MROWS * HID + (size_t)row * HID;
  float vr[4], vi[4];
  float sr = 0.f, si = 0.f;
#pragma unroll
  for (int i = 0; i < 4; i++) { int h = t + i * 256; vr[i] = xr[h]; vi[i] = xi[h]; sr += vr[i]; si += vi[i]; }
  __shared__ float red[2][4];
  for (int m = 1; m < 64; m <<= 1) { sr += __shfl_xor(sr, m); si += __shfl_xor(si, m); }
  int wid = t >> 6, l = t & 63;
  if (l == 0) { red[0][wid] = sr; red[1][wid] = si; }
  __syncthreads();
  float mr = (red[0][0] + red[0][1] + red[0][2] + red[0][3]) * (1.0f / HID);
  float mi = (red[1][0] + red[1][1] + red[1][2] + red[1][3]) * (1.0f / HID);
  float sv = 0.f;
#pragma unroll
  for (int i = 0; i < 4; i++) { float a = vr[i] - mr, b = vi[i] - mi; sv += a * a + b * b; }
  for (int m = 1; m < 64; m <<= 1) sv += __shfl_xor(sv, m);
  __syncthreads();
  if (l == 0) red[0][wid] = sv;
  __syncthreads();
  float var = (red[0][0] + red[0][1] + red[0][2] + red[0][3]) * (1.0f / HID);
  float inv = rsqrtf(var + 1e-5f);
  __bf16* outr = normed + (size_t)row * KD;
#pragma unroll
  for (int i = 0; i < 4; i++) {
    int h = t + i * 256;
    float a = (vr[i] - mr) * inv, b = (vi[i] - mi) * inv;
    float gr = gamma[h], gi = gamma[HID + h], br = beta[h], bi = beta[HID + h];
    outr[h]       = (__bf16)(a * gr - b * gi + br);
    outr[HID + h] = (__bf16)(a * gi + b * gr + bi);
  }
}

// ---------------- pack 4 complex weights [2,1024,1024] -> real B^T [4][2048][2048] bf16 ----------------
__global__ __launch_bounds__(256) void k_packw(const float* __restrict__ qw, const float* __restrict__ kw,
                                               const float* __restrict__ vw, const float* __restrict__ ow,
                                               __bf16* __restrict__ dst) {
  int idx = blockIdx.x * 256 + threadIdx.x;   // 2,097,152 threads, 8 elems each
  int sel = idx >> 19;                        // 0..3: q,k,v,o
  int li  = idx & 524287;
  const float* w = sel == 0 ? qw : (sel == 1 ? kw : (sel == 2 ? vw : ow));
  int o  = li >> 8;
  int k0 = (li & 255) * 8;
  const float* wr = w;
  const float* wi = w + HID * HID;
  int oimag = (o >= HID);
  int oo = o & (HID - 1);
  bf16x8 v;
#pragma unroll
  for (int j = 0; j < 8; j++) {
    int k = k0 + j;
    int kim = (k >= HID);
    int kk = k & (HID - 1);
    float x;
    if (!oimag) x = kim ? -wi[oo * HID + kk] : wr[oo * HID + kk];
    else        x = kim ?  wr[oo * HID + kk] : wi[oo * HID + kk];
    v[j] = (__bf16)x;
  }
  *(bf16x8*)(dst + ((size_t)sel << 22) + (size_t)o * KD + k0) = v;
}

// ---------------- K cache: fp32 copy into nk AND bf16 attn layout Ka ----------------
__global__ __launch_bounds__(256) void k_copyk(const float* __restrict__ kc,
                                               float* __restrict__ nk,
                                               __bf16* __restrict__ Ka) {
  int li = blockIdx.x * 256 + threadIdx.x;   // 2^21 float4 groups
  int c4 = li & 255;
  int kv = (li >> 8) & 2047;
  int b  = (li >> 19) & 1;
  int p  = (li >> 20) & 1;
  f32x4 v = *(const f32x4*)(kc + (((size_t)((p * 2 + b) * 2048 + kv)) << 10) + c4 * 4);
  *(f32x4*)(nk + ((((size_t)(p * 2 + b)) * KVLEN + kv) << 10) + c4 * 4) = v;
  int h = c4 >> 4, d = (c4 & 15) * 4;
  bf16x4 w;
#pragma unroll
  for (int j = 0; j < 4; j++) w[j] = (__bf16)v[j];
  *(bf16x4*)(Ka + (((size_t)(b * 16 + h)) * KVLEN + kv) * 128 + p * 64 + d) = w;
}

// ---------------- v_cache fp32 -> nv fp32 copy + Vattn bf16 transposed (cache half) --------
__global__ __launch_bounds__(256) void k_buildv(const float* __restrict__ vc,
                                                float* __restrict__ nv,
                                                __bf16* __restrict__ dst) {
  __shared__ float tile[32][129];
  int kt = blockIdx.x;            // kv tile (32 rows), 64 tiles = cache half
  int bh = blockIdx.y;
  int b = bh >> 4, h = bh & 15;
  int t = threadIdx.x;
  int kv0 = kt * 32;
#pragma unroll
  for (int i = 0; i < 16; i++) {
    int idx = i * 256 + t;
    int kvl = idx >> 7, dsl = idx & 127;
    int p = dsl >> 6, d = dsl & 63;
    float v = vc[(((size_t)(p * 2 + b)) * CACHE + kv0 + kvl) * HID + h * 64 + d];
    tile[kvl][dsl] = v;
    nv[(((size_t)(p * 2 + b)) * KVLEN + kv0 + kvl) * HID + h * 64 + d] = v;
  }
  __syncthreads();
#pragma unroll
  for (int i = 0; i < 16; i++) {
    int idx = i * 256 + t;
    int dsl = idx >> 5, kvl = idx & 31;
    dst[(((size_t)bh) * 128 + dsl) * KVLEN + kv0 + kvl] = (__bf16)tile[kvl][dsl];
  }
}

// ---------------- bf16 GEMM 128x128 tile, BK=64, 4 waves, T2 XOR-swizzled LDS ----------------
// QKV=1: A=normed, B=[wq;wk;wv] (N=6144), n>>11 selects {Qa | nk+Ka | nv+Va} epilogue
// QKV=0: A=attn_out, B=wo, y = x + delta
#define BM 128
#define BN 128
#define BK 64
template <int QKV>
__global__ __launch_bounds__(256, 3) void k_gemm(const __bf16* __restrict__ A,
                                                 const __bf16* __restrict__ Bp,
                                                 const float* __restrict__ bias0,
                                                 const float* __restrict__ bias1,
                                                 const float* __restrict__ bias2,
                                                 const float* __restrict__ hid,
                                                 float* __restrict__ outF0,
                                                 float* __restrict__ outF1,
                                                 __bf16* __restrict__ outB0,
                                                 __bf16* __restrict__ outB1,
                                                 __bf16* __restrict__ outB2) {
  __shared__ __align__(16) __bf16 As[BM * BK];
  __shared__ __align__(16) __bf16 Bs[BN * BK];
  int bm0 = blockIdx.x * BM, bn0 = blockIdx.y * BN;
  int t = threadIdx.x, l = t & 63, wid = t >> 6;
  int wr = wid >> 1, wc = wid & 1;
  int l15 = l & 15, lg = l >> 4;
  f32x4 acc[4][4];
  f32x4 zero = {0.f, 0.f, 0.f, 0.f};
#pragma unroll
  for (int i = 0; i < 4; i++)
#pragma unroll
    for (int j = 0; j < 4; j++) acc[i][j] = zero;
  const __bf16* Ab = A + (size_t)bm0 * KD;
  const __bf16* Bb = Bp + (size_t)bn0 * KD;
  for (int k0 = 0; k0 < KD; k0 += BK) {
    // stage: LDS dest linear (global_load_lds), global source column pre-swizzled:
    // LDS[row][slot s] = global[row][s ^ (row&7)]  (16B slots)
#pragma unroll
    for (int c = 0; c < 4; c++) {
      int idx = c * 256 + t;
      int row = idx >> 3, ch = idx & 7;
      int chs = ch ^ (row & 7);
      gload_lds16(Ab + (size_t)row * KD + k0 + chs * 8, As + idx * 8);
      gload_lds16(Bb + (size_t)row * KD + k0 + chs * 8, Bs + idx * 8);
    }
    __syncthreads();
#pragma unroll
    for (int ks = 0; ks < 2; ks++) {
      bf16x8 af[4], bfv[4];
#pragma unroll
      for (int i = 0; i < 4; i++) {
        int ra = wr * 64 + i * 16 + l15;
        int rb = wc * 64 + i * 16 + l15;
        af[i]  = *(const bf16x8*)((const char*)As + ra * 128 + ((ks * 64 + lg * 16) ^ ((ra & 7) << 4)));
        bfv[i] = *(const bf16x8*)((const char*)Bs + rb * 128 + ((ks * 64 + lg * 16) ^ ((rb & 7) << 4)));
      }
#pragma unroll
      for (int mi = 0; mi < 4; mi++)
#pragma unroll
        for (int ni = 0; ni < 4; ni++)
          acc[mi][ni] = __builtin_amdgcn_mfma_f32_16x16x32_bf16(af[mi], bfv[ni], acc[mi][ni], 0, 0, 0);
    }
    __syncthreads();
  }
  // epilogue: C[m][n]: m row = (lg*4+j), col = l15 within each 16x16 frag
#pragma unroll
  for (int mi = 0; mi < 4; mi++) {
#pragma unroll
    for (int ni = 0; ni < 4; ni++) {
      int mbase = bm0 + wr * 64 + mi * 16 + lg * 4;     // 4 consecutive m over j
      int n = bn0 + wc * 64 + ni * 16 + l15;
      int b = mbase >> 11, sbase = mbase & 2047;
      if (QKV) {
        int mode = n >> 11, nl = n & 2047;
        const float* bias = mode == 0 ? bias0 : (mode == 1 ? bias1 : bias2);
        float bv = bias[nl];
        int p = nl >> 10, hd = nl & 1023;
        if (mode == 2) {
          bf16x4 w;
#pragma unroll
          for (int j = 0; j < 4; j++) {
            float v = acc[mi][ni][j] + bv;
            outF1[(((size_t)(p * 2 + b)) * KVLEN + (CACHE + sbase + j)) * HID + hd] = v;
            w[j] = (__bf16)v;
          }
          *(bf16x4*)(outB2 + (((size_t)(b * 16 + (hd >> 6))) * 128 + p * 64 + (hd & 63)) * KVLEN + CACHE + sbase) = w;
        } else {
#pragma unroll
          for (int j = 0; j < 4; j++) {
            float v = acc[mi][ni][j] + bv;
            int s = sbase + j;
            if (mode == 0) {
              outB0[(((size_t)(b * 16 + (hd >> 6))) * SEQ + s) * 128 + p * 64 + (hd & 63)] = (__bf16)v;
            } else {
              outF0[(((size_t)(p * 2 + b)) * KVLEN + (CACHE + s)) * HID + hd] = v;
              outB1[(((size_t)(b * 16 + (hd >> 6))) * KVLEN + (CACHE + s)) * 128 + p * 64 + (hd & 63)] = (__bf16)v;
            }
          }
        }
      } else {
        float bv = bias0[n];
        int p = n >> 10;
#pragma unroll
        for (int j = 0; j < 4; j++) {
          float v = acc[mi][ni][j] + bv;
          size_t off = (((size_t)(p * 2 + b)) * SEQ + (sbase + j)) * HID + (n & 1023);
          outF0[off] = v + hid[off];
        }
      }
    }
  }
}

// ---------------- flash attention: 8 waves x 16 q-rows (QBLK=128), 64-kv tiles, d=128 ----------
// r8's double-buffered counted-vmcnt pipeline, re-tiled to 8 waves for 4 waves/SIMD.
// No fragment hoisting (register budget: arch ~62 + accum ~36 < 128 cap).
__global__ __launch_bounds__(512, 4) void k_attn(const __bf16* __restrict__ Q,
                                                 const __bf16* __restrict__ Kt,
                                                 const __bf16* __restrict__ Vt,
                                                 __bf16* __restrict__ outp) {
  __shared__ __align__(16) __bf16 Ks[2][64 * 128];
  __shared__ __align__(16) __bf16 Vs[2][128 * 64];
  __shared__ __align__(16) __bf16 Ps[8][16 * 64];
  // 512 blocks: XCD-chunked (4 heads/XCD) + qt pairing (qt, 15-qt) for balance
  int id = blockIdx.y * gridDim.x + blockIdx.x;
  int xcd = id & 7, li = id >> 3;
  int bh = (xcd << 2) | (li >> 4);
  int ql = li & 15;
  int qt = (ql & 1) ? (15 - (ql >> 1)) : (ql >> 1);
  int b = bh >> 4, h = bh & 15;
  int t = threadIdx.x, l = t & 63, wid = t >> 6;
  int l15 = l & 15, lg = l >> 4;
  const __bf16* Qb = Q + ((size_t)bh * SEQ) * 128;
  const __bf16* Kb = Kt + ((size_t)bh * KVLEN) * 128;
  const __bf16* Vb = Vt + ((size_t)bh * 128) * KVLEN;
  __bf16* Pw = &Ps[wid][0];
  int q0 = qt * 128 + wid * 16;
  bf16x8 aQ[4];
#pragma unroll
  for (int dk = 0; dk < 4; dk++)
    aQ[dk] = *(const bf16x8*)(Qb + (size_t)(q0 + l15) * 128 + dk * 32 + lg * 8);
  f32x4 zero = {0.f, 0.f, 0.f, 0.f};
  f32x4 o[8];
  f32x4 sums = zero;
#pragma unroll
  for (int df = 0; df < 8; df++) o[df] = zero;
  bf16x8 ones;
#pragma unroll
  for (int i = 0; i < 8; i++) ones[i] = (__bf16)1.0f;
  const int nfull = 32 + 2 * qt;   // unmasked 64-kv tiles for this 128-q block
  const int nt = nfull + 2;
  int sw = (l15 & 7) << 4;
  int rx = (l15 & 7) << 3;         // P element-index XOR (P row = l15)

  auto STAGE = [&](int bb, int ti) {
    int kv0 = ti * 64;
#pragma unroll
    for (int c = 0; c < 2; c++) {
      int idx = c * 512 + t;             // 0..1023
      int kr = idx >> 4;                 // K row (16 slots x 16B per 256B row)
      gload_lds16(Kb + (size_t)(kv0 + kr) * 128 + (((idx & 15) ^ (kr & 7)) << 3), &Ks[bb][idx * 8]);
      int vr = idx >> 3;                 // V row (8 slots x 16B per 128B row)
      gload_lds16(Vb + (size_t)vr * KVLEN + kv0 + (((idx & 7) ^ (vr & 7)) << 3), &Vs[bb][idx * 8]);
    }
  };

  STAGE(0, 0);
  for (int ti = 0; ti < nt; ti++) {
    int bb = ti & 1;
    if (ti + 1 < nt) {
      STAGE(bb ^ 1, ti + 1);
      asm volatile("s_waitcnt vmcnt(4)" ::: "memory");   // current tile's 4 loads done; next 4 in flight
    } else {
      asm volatile("s_waitcnt vmcnt(0)" ::: "memory");
    }
    __builtin_amdgcn_s_barrier();
    // ---- QK^T (swapped: A=K, B=Q -> C row=kv-local, col=q-local) ----
    const char* KsB = (const char*)&Ks[bb][0];
    const char* VsB = (const char*)&Vs[bb][0];
    f32x4 sacc[4];
    __builtin_amdgcn_s_setprio(1);
#pragma unroll
    for (int kvf = 0; kvf < 4; kvf++) {
      sacc[kvf] = zero;
      const char* kbase = KsB + (kvf * 16 + l15) * 256;
#pragma unroll
      for (int dk = 0; dk < 4; dk++) {
        bf16x8 bK = *(const bf16x8*)(kbase + ((dk * 64 + lg * 16) ^ sw));
        sacc[kvf] = __builtin_amdgcn_mfma_f32_16x16x32_bf16(bK, aQ[dk], sacc[kvf], 0, 0, 0);
      }
    }
    __builtin_amdgcn_s_setprio(0);
    // ---- softmax: lane owns q=l15, kv=kvf*16+lg*4+j -> packed bf16x4 P writes ----
    bool masked = (ti >= nfull);
    int lim = qt * 128 + wid * 16 + l15 - (ti - 32) * 64;  // mask if kv_local > lim
#pragma unroll
    for (int kvf = 0; kvf < 4; kvf++) {
      bf16x4 w;
#pragma unroll
      for (int j = 0; j < 4; j++) {
        float p = exp2f(sacc[kvf][j] * 0.18033688011112042f);  // 1/sqrt(64)*log2(e)
        if (masked && (kvf * 16 + lg * 4 + j > lim)) p = 0.f;
        w[j] = (__bf16)p;
      }
      *(bf16x4*)(Pw + l15 * 64 + ((kvf * 16 + lg * 4) ^ rx)) = w;
    }
    // ---- PV + row-sum via ones-MFMA (fragments read inline, no hoist) ----
    __builtin_amdgcn_s_setprio(1);
#pragma unroll
    for (int ks = 0; ks < 2; ks++) {
      bf16x8 aP = *(const bf16x8*)(Pw + l15 * 64 + ((ks * 32 + lg * 8) ^ rx));
      sums = __builtin_amdgcn_mfma_f32_16x16x32_bf16(aP, ones, sums, 0, 0, 0);
      int off = (ks * 64 + lg * 16) ^ sw;
#pragma unroll
      for (int df = 0; df < 8; df++) {
        bf16x8 bV = *(const bf16x8*)(VsB + (df * 16 + l15) * 128 + off);
        o[df] = __builtin_amdgcn_mfma_f32_16x16x32_bf16(aP, bV, o[df], 0, 0, 0);
      }
    }
    __builtin_amdgcn_s_setprio(0);
    __builtin_amdgcn_s_barrier();
  }
  // ---- write attn_out [4096][2048] bf16 (real cols 0..1023, imag 1024..2047) ----
  float inv[4];
#pragma unroll
  for (int j = 0; j < 4; j++) inv[j] = 1.0f / sums[j];
#pragma unroll
  for (int df = 0; df < 8; df++) {
    int dslot = df * 16 + l15;
    int col = (dslot < 64) ? (h * 64 + dslot) : (1024 + h * 64 + (dslot - 64));
#pragma unroll
    for (int j = 0; j < 4; j++) {
      int qg2 = q0 + lg * 4 + j;
      float v = o[df][j] * inv[j];
      outp[((size_t)(b * SEQ + qg2)) * KD + col] = (__bf16)v;
    }
  }
}

extern "C" void kernel_launch(void* const* d_in, const int* in_sizes, int n_in,
                              void* d_out, int out_size, void* d_ws, size_t ws_size,
                              hipStream_t stream) {
  const float* hid = (const float*)d_in[0];
  const float* kc  = (const float*)d_in[1];
  const float* vc  = (const float*)d_in[2];
  const float* qw  = (const float*)d_in[3];
  const float* qb  = (const float*)d_in[4];
  const float* kw  = (const float*)d_in[5];
  const float* kb  = (const float*)d_in[6];
  const float* vw  = (const float*)d_in[7];
  const float* vb  = (const float*)d_in[8];
  const float* ow  = (const float*)d_in[9];
  const float* ob  = (const float*)d_in[10];
  const float* lg  = (const float*)d_in[11];
  const float* lb  = (const float*)d_in[12];

  float* y  = (float*)d_out;                 // [2,B,S,H]       8,388,608 f32
  float* nk = y + 8388608;                   // [2,B,4096,16,64] 16,777,216 f32
  float* nv = nk + 16777216;

  char* ws = (char*)d_ws;
  __bf16* normed = (__bf16*)(ws);                  // 16 MB [4096][2048]
  __bf16* wall   = (__bf16*)(ws + 16777216);       // 32 MB [4][2048][2048] q,k,v,o
  __bf16* Qa     = (__bf16*)(ws + 50331648);       // 16 MB [32][2048][128]
  __bf16* Ka     = (__bf16*)(ws + 67108864);       // 32 MB [32][4096][128]
  __bf16* Va     = (__bf16*)(ws + 100663296);      // 32 MB [32][128][4096]
  __bf16* ao     = (__bf16*)(ws + 134217728);      // 16 MB [4096][2048]

  k_layernorm<<<4096, 256, 0, stream>>>(hid, lg, lb, normed);
  k_packw<<<8192, 256, 0, stream>>>(qw, kw, vw, ow, wall);
  k_copyk<<<8192, 256, 0, stream>>>(kc, nk, Ka);
  dim3 gv(64, 32);
  k_buildv<<<gv, 256, 0, stream>>>(vc, nv, Va);
  dim3 gq(32, 48);
  k_gemm<1><<<gq, 256, 0, stream>>>(normed, wall, qb, kb, vb, nullptr, nk, nv, Qa, Ka, Va);
  dim3 ga(16, 32);
  k_attn<<<ga, 512, 0, stream>>>(Qa, Ka, Va, ao);
  dim3 go(32, 16);
  k_gemm<0><<<go, 256, 0, stream>>>(ao, wall + ((size_t)3 << 22), ob, nullptr, nullptr, hid, y, nullptr, nullptr, nullptr, nullptr);
}